// Round 7
// baseline (175.011 us; speedup 1.0000x reference)
//
#include <hip/hip_runtime.h>
#include <hip/hip_bf16.h>

#define BATCH 4
#define SEQ   2048
#define DM    512
#define NH    8
#define HD    64
#define PART  (BATCH*NH*SEQ*HD)   /* 4,194,304 = M*DM */
#define QSCALE 0.18033688f        /* (1/sqrt(64)) * log2(e) : folded into Q */

typedef unsigned short u16;
typedef unsigned int   u32;
typedef __bf16 bf16x8 __attribute__((ext_vector_type(8)));
typedef float  f32x4  __attribute__((ext_vector_type(4)));
typedef float  f32x16 __attribute__((ext_vector_type(16)));
typedef unsigned int u32x2 __attribute__((ext_vector_type(2)));

__device__ __forceinline__ u16 f2bf(float f) {
    union { float f; u32 u; } v; v.f = f;
    u32 r = v.u + 0x7fffu + ((v.u >> 16) & 1u);   // RNE
    return (u16)(r >> 16);
}

// async global->LDS, 16B per lane; LDS dest = uniform base + lane*16
__device__ __forceinline__ void glds16(const u16* g, u16* lds) {
    __builtin_amdgcn_global_load_lds(
        (const __attribute__((address_space(1))) void*)g,
        (__attribute__((address_space(3))) void*)lds, 16, 0, 0);
}

// v_permlane32_swap_b32: a.hi-lanes <-> b.lo-lanes
__device__ __forceinline__ void pl32swap(u32 &a, u32 &b) {
    u32x2 r = __builtin_amdgcn_permlane32_swap(a, b, false, false);
    a = r[0]; b = r[1];
}

// ---------------------------------------------------------------------------
// prep: z=0 -> f32->bf16 convert of x (512 blocks, grid-stride)
//       z=1 -> transpose w_qkv (192 blocks)   z=2 -> transpose w_out (64)
// ---------------------------------------------------------------------------
__global__ __launch_bounds__(256) void prep_k(
    const float* __restrict__ x, u16* __restrict__ xb,
    const float* __restrict__ w_qkv, u16* __restrict__ t_qkv,
    const float* __restrict__ w_out, u16* __restrict__ t_out)
{
    __shared__ u16 Ts[64][72];
    const int z = blockIdx.z, bx = blockIdx.x, t = threadIdx.x;

    if (z == 0) {
        const int n8 = PART / 8;
        for (int i = bx * 256 + t; i < n8; i += 512 * 256) {
            float4 a = *(const float4*)(x + (size_t)i * 8);
            float4 b = *(const float4*)(x + (size_t)i * 8 + 4);
            union { uint4 v; u16 s[8]; } o;
            o.s[0] = f2bf(a.x); o.s[1] = f2bf(a.y);
            o.s[2] = f2bf(a.z); o.s[3] = f2bf(a.w);
            o.s[4] = f2bf(b.x); o.s[5] = f2bf(b.y);
            o.s[6] = f2bf(b.z); o.s[7] = f2bf(b.w);
            *(uint4*)(xb + (size_t)i * 8) = o.v;
        }
        return;
    }
    const int N = (z == 1) ? 3 * DM : DM;
    const int ntiles = N / 64;
    if (bx >= ntiles * 8) return;
    const float* W = (z == 1) ? w_qkv : w_out;
    u16* Wt = (z == 1) ? t_qkv : t_out;
    const int n0 = (bx % ntiles) * 64, k0 = (bx / ntiles) * 64;

    #pragma unroll
    for (int l = 0; l < 4; ++l) {
        int idx = l * 1024 + t * 4;
        int r = idx >> 6, c = idx & 63;
        float4 v = *(const float4*)(W + (size_t)(k0 + r) * N + n0 + c);
        Ts[c + 0][r] = f2bf(v.x);
        Ts[c + 1][r] = f2bf(v.y);
        Ts[c + 2][r] = f2bf(v.z);
        Ts[c + 3][r] = f2bf(v.w);
    }
    __syncthreads();
    #pragma unroll
    for (int l = 0; l < 2; ++l) {
        int idx = l * 256 + t;
        int row = idx >> 3, ch = idx & 7;
        *(uint4*)(Wt + (size_t)(n0 + row) * DM + k0 + ch * 8) =
            *(const uint4*)(&Ts[row][ch * 8]);
    }
}

// ---------------------------------------------------------------------------
// GEMM: C(M,N) = A(M,K)bf16 @ Bt(N,K)^T bf16 + bias(N)f32.
// Double-buffered LDS, one barrier per K-step.
// MODE 0: BM=128; scatter into ws: Q (prescaled) | K (B,H,S,HD); V^T (B,H,HD,S).
// MODE 1: BM=64 (grid 128x4 = 512 blocks, 2/CU); row-major f32 store.
// ---------------------------------------------------------------------------
template<int MODE>
__global__ __launch_bounds__(256) void gemm_k(
    const u16* __restrict__ A, const u16* __restrict__ Bt,
    const float* __restrict__ bias, void* __restrict__ outv,
    int M, int N, int K)
{
    constexpr int BM = (MODE == 1) ? 64 : 128;
    constexpr int NI = (MODE == 1) ? 2 : 4;

    __shared__ __align__(16) u16 As[2][BM * 32];
    __shared__ __align__(16) u16 Bs[2][128 * 32];

    const int tid  = threadIdx.x;
    const int bm0  = blockIdx.x * BM;
    const int bn0  = blockIdx.y * 128;
    const int wave = tid >> 6, lane = tid & 63;
    const int l16  = lane & 15, quad = lane >> 4;
    const int wr   = (MODE == 1) ? 0 : (wave & 1) * 64;
    const int wc   = (MODE == 1) ? wave * 32 : (wave >> 1) * 64;

    const int srow = (lane >> 2);            // 0..15
    const int scol = (lane & 3) * 8;         // 0,8,16,24
    const int arow = (MODE == 1) ? (wave * 16) : (wave * 32);
    const u16* Ag = A + (size_t)(bm0 + arow + srow) * K + scol;
    const u16* Bg = Bt + (size_t)(bn0 + wave * 32 + srow) * K + scol;
    const int wofsA = arow * 32;
    const int wofsB = (wave * 32) * 32;

    f32x4 acc[4][NI];
    #pragma unroll
    for (int i = 0; i < 4; ++i)
        #pragma unroll
        for (int j = 0; j < NI; ++j)
            acc[i][j] = (f32x4){0.f, 0.f, 0.f, 0.f};

    glds16(Ag, &As[0][wofsA]);
    if (MODE == 0) glds16(Ag + (size_t)16 * K, &As[0][wofsA + 16 * 32]);
    glds16(Bg,                  &Bs[0][wofsB]);
    glds16(Bg + (size_t)16 * K, &Bs[0][wofsB + 16 * 32]);
    __syncthreads();

    const int NIT = K >> 5;
    for (int it = 0; it < NIT; ++it) {
        const int cur = it & 1;
        if (it + 1 < NIT) {
            const int nx = cur ^ 1;
            const int k0 = (it + 1) << 5;
            glds16(Ag + k0, &As[nx][wofsA]);
            if (MODE == 0) glds16(Ag + k0 + (size_t)16 * K, &As[nx][wofsA + 16 * 32]);
            glds16(Bg + k0,                  &Bs[nx][wofsB]);
            glds16(Bg + k0 + (size_t)16 * K, &Bs[nx][wofsB + 16 * 32]);
        }

        bf16x8 af[4], bfr[NI];
        #pragma unroll
        for (int mi = 0; mi < 4; ++mi)
            af[mi] = *(const bf16x8*)(&As[cur][(wr + mi * 16 + l16) * 32 + quad * 8]);
        #pragma unroll
        for (int ni = 0; ni < NI; ++ni)
            bfr[ni] = *(const bf16x8*)(&Bs[cur][(wc + ni * 16 + l16) * 32 + quad * 8]);
        #pragma unroll
        for (int mi = 0; mi < 4; ++mi)
            #pragma unroll
            for (int ni = 0; ni < NI; ++ni)
                acc[mi][ni] = __builtin_amdgcn_mfma_f32_16x16x32_bf16(
                    af[mi], bfr[ni], acc[mi][ni], 0, 0, 0);
        __syncthreads();
    }

    #pragma unroll
    for (int mi = 0; mi < 4; ++mi) {
        #pragma unroll
        for (int ni = 0; ni < NI; ++ni) {
            int col = bn0 + wc + ni * 16 + l16;
            float bv = bias[col];
            int row0 = bm0 + wr + mi * 16 + quad * 4;
            float v[4];
            #pragma unroll
            for (int reg = 0; reg < 4; ++reg) v[reg] = acc[mi][ni][reg] + bv;

            if (MODE == 1) {
                #pragma unroll
                for (int reg = 0; reg < 4; ++reg)
                    ((float*)outv)[(size_t)(row0 + reg) * N + col] = v[reg];
            } else {
                u16* ws = (u16*)outv;
                int part = col >> 9, wi = col & 511;
                int h = wi >> 6, e = wi & 63;
                int b = row0 >> 11, s0 = row0 & 2047;
                if (part == 2) {
                    union { u16 q[4]; uint2 u; } pk;
                    #pragma unroll
                    for (int reg = 0; reg < 4; ++reg) pk.q[reg] = f2bf(v[reg]);
                    *(uint2*)(ws + (size_t)2 * PART +
                              ((size_t)(b * NH + h) * HD + e) * SEQ + s0) = pk.u;
                } else {
                    float scl = (part == 0) ? QSCALE : 1.0f;
                    #pragma unroll
                    for (int reg = 0; reg < 4; ++reg)
                        ws[(size_t)part * PART +
                           ((size_t)(b * NH + h) * SEQ + s0 + reg) * HD + e] =
                            f2bf(v[reg] * scl);
                }
            }
        }
    }
}

// ---------------------------------------------------------------------------
// Causal flash attention, swapped-QK 32x32 MFMA, in-register P (T12).
// FULL-STRIP round: block = 4 waves, each wave = one 32q x 64kv strip of a
// 128q x 64kv tile (no kh split). Halves block-tiles (8704 vs 16896),
// halves staged K/V bytes, halves barriers, and ELIMINATES the kv-half
// merge (no Ob scratch, no merge barriers; epilogue is wave-private).
// Two independent QK chains (st0/st1) + 32 exp2 per lane = 2x in-wave ILP.
// Causal per wave: tiles kt <= mylim = 2qb + (qh>>1); on the diag tile,
// qh even -> mask half0 (kvl>l31) + zero half1; qh odd -> mask half1.
// Staging/swizzle algebra byte-identical to the proven R4 kernel.
// Grid (bh=32, y=16), qb = 15-y big-first LPT. LDS 33.3 KB, 4 blocks/CU.
// ---------------------------------------------------------------------------
__global__ __launch_bounds__(256, 4) void attn_k(
    const u16* __restrict__ Q, const u16* __restrict__ K,
    const u16* __restrict__ Vt, u16* __restrict__ O)
{
    __shared__ __align__(16) u16 KsB[2][64 * 64];   // [kv][d], chunk-swizzled
    __shared__ __align__(16) u16 VtB[2][64 * 64];   // [d][kv], chunk-swizzled
    __shared__ float Lred[4][32];

    const int bh = blockIdx.x;
    const int qb = 15 - blockIdx.y;            // big q-blocks dispatched first
    const int tid = threadIdx.x, wave = tid >> 6, lane = tid & 63;
    const int l31 = lane & 31, hi = lane >> 5, x7 = lane & 7;
    const int qh = wave;                       // 0..3 : 32-q strip per wave
    const size_t baseK = (size_t)bh * SEQ * HD;
    const size_t baseV = (size_t)bh * HD * SEQ;
    const int b = bh >> 3, h = bh & 7;

    // glds lane source addressing (XOR chunk swizzle at the source)
    const int sub = lane >> 3;                 // 0..7
    const int lcx = (lane & 7) ^ sub;          // logical 16B chunk for this lane
    const u16* kg = K  + baseK + (size_t)((wave * 16 + sub) * 64)   + lcx * 8;
    const u16* vg = Vt + baseV + (size_t)((wave * 16 + sub) * 2048) + lcx * 8;
    u16* ksd = &KsB[0][wave * 1024];
    u16* vtd = &VtB[0][wave * 1024];

    // fragment LDS element offsets (swizzle: phys chunk = logical ^ (row&7);
    // every read row has row&7 == lane&7)
    int koff[2][4], voff[2][4];
    #pragma unroll
    for (int kvh = 0; kvh < 2; ++kvh)
        #pragma unroll
        for (int k = 0; k < 4; ++k)
            koff[kvh][k] = (kvh * 32 + l31) * 64 + (((k << 1) + hi) ^ x7) * 8;
    #pragma unroll
    for (int dt = 0; dt < 2; ++dt)
        #pragma unroll
        for (int s = 0; s < 4; ++s)
            voff[dt][s] = (dt * 32 + l31) * 64 + (((s << 1) + hi) ^ x7) * 8;

    // ---- Q fragments direct from global (rows q = qb*128 + qh*32 + l31) ----
    const u16* qg = Q + baseK + (size_t)(qb * 128 + qh * 32 + l31) * 64 + hi * 8;
    bf16x8 qf[4];
    #pragma unroll
    for (int k = 0; k < 4; ++k)
        qf[k] = *(const bf16x8*)(qg + k * 16);

    // prefetch kt=0 into buffer 0
    glds16(kg,            ksd);
    glds16(kg + 8 * 64,   ksd + 512);
    glds16(vg,            vtd);
    glds16(vg + 8 * 2048, vtd + 512);
    __syncthreads();   // vmcnt(0) drain: buf0 landed

    float la0 = 0.f, la1 = 0.f;
    f32x16 o0, o1;
    #pragma unroll
    for (int i = 0; i < 16; ++i) { o0[i] = 0.f; o1[i] = 0.f; }

    const int mylim = 2 * qb + (qh >> 1);      // last (diagonal) tile for wave
    const int NT = 2 * qb + 2;                 // tiles staged by the block
    for (int kt = 0; kt < NT; ++kt) {
        const int cur = kt & 1;
        if (kt + 1 < NT) {
            const int nx = (cur ^ 1) * 4096;
            glds16(kg + (size_t)(kt + 1) * 4096,          ksd + nx);
            glds16(kg + (size_t)(kt + 1) * 4096 + 8 * 64, ksd + nx + 512);
            glds16(vg + (size_t)(kt + 1) * 64,            vtd + nx);
            glds16(vg + (size_t)(kt + 1) * 64 + 8 * 2048, vtd + nx + 512);
        }

        if (kt <= mylim) {                     // wave-uniform causal activity
            // ---- QK^T: two independent 32x32 chains over kv halves ----
            bf16x8 kf[4];
            f32x16 st0, st1;
            #pragma unroll
            for (int i = 0; i < 16; ++i) { st0[i] = 0.f; st1[i] = 0.f; }
            #pragma unroll
            for (int k = 0; k < 4; ++k)
                kf[k] = *(const bf16x8*)(&KsB[cur][koff[0][k]]);
            __builtin_amdgcn_s_setprio(1);
            #pragma unroll
            for (int k = 0; k < 4; ++k)
                st0 = __builtin_amdgcn_mfma_f32_32x32x16_bf16(
                    kf[k], qf[k], st0, 0, 0, 0);
            __builtin_amdgcn_s_setprio(0);
            #pragma unroll
            for (int k = 0; k < 4; ++k)
                kf[k] = *(const bf16x8*)(&KsB[cur][koff[1][k]]);
            __builtin_amdgcn_s_setprio(1);
            #pragma unroll
            for (int k = 0; k < 4; ++k)
                st1 = __builtin_amdgcn_mfma_f32_32x32x16_bf16(
                    kf[k], qf[k], st1, 0, 0, 0);
            __builtin_amdgcn_s_setprio(0);

            // p[r]: kv = 32*half + (r&3)+8*(r>>2)+4*hi, q = l31
            float p[32];
            #pragma unroll
            for (int r = 0; r < 16; ++r) {
                p[r]      = __builtin_amdgcn_exp2f(st0[r]);
                p[16 + r] = __builtin_amdgcn_exp2f(st1[r]);
            }
            if (kt == mylim) {                 // diagonal tile masking
                if ((qh & 1) == 0) {
                    #pragma unroll
                    for (int r = 0; r < 16; ++r) {
                        int kvl = (r & 3) + 8 * (r >> 2) + 4 * hi;
                        if (kvl > l31) p[r] = 0.f;
                        p[16 + r] = 0.f;
                    }
                } else {
                    #pragma unroll
                    for (int r = 0; r < 16; ++r) {
                        int kvl = (r & 3) + 8 * (r >> 2) + 4 * hi;
                        if (kvl > l31) p[16 + r] = 0.f;
                    }
                }
            }
            #pragma unroll
            for (int r = 0; r < 16; ++r) { la0 += p[r]; la1 += p[16 + r]; }

            // pack to bf16; permlane32_swap builds 4 PV A-fragments (kv 16-slices)
            u32 c[8], d[8];
            #pragma unroll
            for (int m = 0; m < 8; ++m) {
                __hip_bfloat162 t0 =
                    __float22bfloat162_rn(float2{p[2 * m], p[2 * m + 1]});
                __hip_bfloat162 t1 =
                    __float22bfloat162_rn(float2{p[16 + 2 * m], p[16 + 2 * m + 1]});
                c[m] = *(u32*)&t0;
                d[m] = *(u32*)&t1;
            }
            pl32swap(c[0], c[2]); pl32swap(c[1], c[3]);
            pl32swap(c[4], c[6]); pl32swap(c[5], c[7]);
            pl32swap(d[0], d[2]); pl32swap(d[1], d[3]);
            pl32swap(d[4], d[6]); pl32swap(d[5], d[7]);
            union { u32 w[4]; bf16x8 v; } pa0, pa1, pa2, pa3;
            pa0.w[0] = c[0]; pa0.w[1] = c[1]; pa0.w[2] = c[2]; pa0.w[3] = c[3];
            pa1.w[0] = c[4]; pa1.w[1] = c[5]; pa1.w[2] = c[6]; pa1.w[3] = c[7];
            pa2.w[0] = d[0]; pa2.w[1] = d[1]; pa2.w[2] = d[2]; pa2.w[3] = d[3];
            pa3.w[0] = d[4]; pa3.w[1] = d[5]; pa3.w[2] = d[6]; pa3.w[3] = d[7];

            // ---- PV: O[q][d] += P @ V, K-dim = 64 kv (4 slices) ----
            bf16x8 vf0[4], vf1[4];
            #pragma unroll
            for (int s = 0; s < 4; ++s) {
                vf0[s] = *(const bf16x8*)(&VtB[cur][voff[0][s]]);
                vf1[s] = *(const bf16x8*)(&VtB[cur][voff[1][s]]);
            }
            __builtin_amdgcn_s_setprio(1);
            o0 = __builtin_amdgcn_mfma_f32_32x32x16_bf16(pa0.v, vf0[0], o0, 0, 0, 0);
            o0 = __builtin_amdgcn_mfma_f32_32x32x16_bf16(pa1.v, vf0[1], o0, 0, 0, 0);
            o0 = __builtin_amdgcn_mfma_f32_32x32x16_bf16(pa2.v, vf0[2], o0, 0, 0, 0);
            o0 = __builtin_amdgcn_mfma_f32_32x32x16_bf16(pa3.v, vf0[3], o0, 0, 0, 0);
            o1 = __builtin_amdgcn_mfma_f32_32x32x16_bf16(pa0.v, vf1[0], o1, 0, 0, 0);
            o1 = __builtin_amdgcn_mfma_f32_32x32x16_bf16(pa1.v, vf1[1], o1, 0, 0, 0);
            o1 = __builtin_amdgcn_mfma_f32_32x32x16_bf16(pa2.v, vf1[2], o1, 0, 0, 0);
            o1 = __builtin_amdgcn_mfma_f32_32x32x16_bf16(pa3.v, vf1[3], o1, 0, 0, 0);
            __builtin_amdgcn_s_setprio(0);
        }
        __syncthreads();   // all waves done with buf[cur]; prefetch drained
    }

    // ---- wave-private epilogue: row-sum, normalize, store ----
    float l2 = (la0 + la1);
    l2 += __shfl_xor(l2, 32);            // combine hi halves (same q)
    if (lane < 32) Lred[wave][lane] = l2;   // wave-private row; lgkm orders
    #pragma unroll
    for (int r = 0; r < 16; ++r) {
        int ql = (r & 3) + 8 * (r >> 2) + 4 * hi;       // q row 0..31
        float lt = Lred[wave][ql];
        int srow = qb * 128 + qh * 32 + ql;
        size_t idx = (((size_t)(b * SEQ + srow)) * NH + h) * HD + l31;
        O[idx]      = f2bf(o0[r] / lt);
        O[idx + 32] = f2bf(o1[r] / lt);
    }
}

extern "C" void kernel_launch(void* const* d_in, const int* in_sizes, int n_in,
                              void* d_out, int out_size, void* d_ws, size_t ws_size,
                              hipStream_t stream) {
    const float* x     = (const float*)d_in[0];
    const float* w_qkv = (const float*)d_in[1];
    const float* b_qkv = (const float*)d_in[2];
    const float* w_out = (const float*)d_in[3];
    const float* b_out = (const float*)d_in[4];

    u16* qkv    = (u16*)d_ws;                       // Q | K | V^T, each PART
    u16* attn   = qkv + (size_t)3 * PART;           // PART bf16 (B,S,H,HD)
    u16* xb     = attn + (size_t)PART;              // PART bf16 (x converted)
    u16* wt_qkv = xb + (size_t)PART;                // 1536*512 bf16
    u16* wt_out = wt_qkv + (size_t)(3 * DM) * DM;   // 512*512 bf16

    const int M = BATCH * SEQ;                      // 8192

    prep_k<<<dim3(512, 1, 3), 256, 0, stream>>>(x, xb, w_qkv, wt_qkv,
                                                w_out, wt_out);

    dim3 g1(M / 128, (3 * DM) / 128);               // 64 x 12
    gemm_k<0><<<g1, 256, 0, stream>>>(xb, wt_qkv, b_qkv, qkv, M, 3 * DM, DM);

    dim3 g2(BATCH * NH, 16);                        // bh x qb (big-first LPT)
    attn_k<<<g2, 256, 0, stream>>>(qkv, qkv + PART, qkv + 2 * (size_t)PART, attn);

    dim3 g3(M / 64, DM / 128);                      // 128 x 4 = 512 blocks
    gemm_k<1><<<g3, 256, 0, stream>>>(attn, wt_out, b_out, (float*)d_out, M, DM, DM);
}

// Round 9
// 150.150 us; speedup vs baseline: 1.1656x; 1.1656x over previous
//
#include <hip/hip_runtime.h>
#include <hip/hip_bf16.h>

#define BATCH 4
#define SEQ   2048
#define DM    512
#define NH    8
#define HD    64
#define PART  (BATCH*NH*SEQ*HD)   /* 4,194,304 = M*DM */
#define QSCALE 0.18033688f        /* (1/sqrt(64)) * log2(e) : folded into Q */

typedef unsigned short u16;
typedef unsigned int   u32;
typedef __bf16 bf16x8 __attribute__((ext_vector_type(8)));
typedef float  f32x4  __attribute__((ext_vector_type(4)));
typedef float  f32x16 __attribute__((ext_vector_type(16)));
typedef unsigned int u32x2 __attribute__((ext_vector_type(2)));

__device__ __forceinline__ u16 f2bf(float f) {
    union { float f; u32 u; } v; v.f = f;
    u32 r = v.u + 0x7fffu + ((v.u >> 16) & 1u);   // RNE
    return (u16)(r >> 16);
}

// async global->LDS, 16B per lane; LDS dest = uniform base + lane*16
__device__ __forceinline__ void glds16(const u16* g, u16* lds) {
    __builtin_amdgcn_global_load_lds(
        (const __attribute__((address_space(1))) void*)g,
        (__attribute__((address_space(3))) void*)lds, 16, 0, 0);
}

// v_permlane32_swap_b32: a.hi-lanes <-> b.lo-lanes
__device__ __forceinline__ void pl32swap(u32 &a, u32 &b) {
    u32x2 r = __builtin_amdgcn_permlane32_swap(a, b, false, false);
    a = r[0]; b = r[1];
}

// ---------------------------------------------------------------------------
// prep: weight transposes only (x-convert fused into gemm0 A-staging).
// z=0 -> transpose w_qkv (192 blocks)   z=1 -> transpose w_out (64 blocks)
// ---------------------------------------------------------------------------
__global__ __launch_bounds__(256) void prep_k(
    const float* __restrict__ w_qkv, u16* __restrict__ t_qkv,
    const float* __restrict__ w_out, u16* __restrict__ t_out)
{
    __shared__ u16 Ts[64][72];
    const int z = blockIdx.z, bx = blockIdx.x, t = threadIdx.x;
    const int N = (z == 0) ? 3 * DM : DM;
    const int ntiles = N / 64;
    if (bx >= ntiles * 8) return;
    const float* W = (z == 0) ? w_qkv : w_out;
    u16* Wt = (z == 0) ? t_qkv : t_out;
    const int n0 = (bx % ntiles) * 64, k0 = (bx / ntiles) * 64;

    #pragma unroll
    for (int l = 0; l < 4; ++l) {
        int idx = l * 1024 + t * 4;
        int r = idx >> 6, c = idx & 63;
        float4 v = *(const float4*)(W + (size_t)(k0 + r) * N + n0 + c);
        Ts[c + 0][r] = f2bf(v.x);
        Ts[c + 1][r] = f2bf(v.y);
        Ts[c + 2][r] = f2bf(v.z);
        Ts[c + 3][r] = f2bf(v.w);
    }
    __syncthreads();
    #pragma unroll
    for (int l = 0; l < 2; ++l) {
        int idx = l * 256 + t;
        int row = idx >> 3, ch = idx & 7;
        *(uint4*)(Wt + (size_t)(n0 + row) * DM + k0 + ch * 8) =
            *(const uint4*)(&Ts[row][ch * 8]);
    }
}

// ---------------------------------------------------------------------------
// GEMM: C(M,N) = A(M,K) @ Bt(N,K)^T bf16 + bias(N)f32.
// MODE 0: A = x in f32, converted in-register during staging (prep-z0 fused);
//         BM=128; scatter into ws: Q (prescaled) | K (B,H,S,HD) | V^T.
//         V^T blocks (bn0>=1024, block-uniform) transpose the 128x128 tile
//         through LDS (pad 136) and store 16-B chunks over 256-B-contiguous
//         s-runs. (Fixed R8 bug: store offset uses s0 = bm0 & 2047, not bm0.)
// MODE 1: A bf16 via glds16; BM=64; row-major f32 store. (unchanged)
// ---------------------------------------------------------------------------
template<int MODE>
__global__ __launch_bounds__(256) void gemm_k(
    const void* __restrict__ Araw, const u16* __restrict__ Bt,
    const float* __restrict__ bias, void* __restrict__ outv,
    int M, int N, int K)
{
    constexpr int BM = (MODE == 1) ? 64 : 128;
    constexpr int NI = (MODE == 1) ? 2 : 4;
    constexpr int ASZ = 2 * BM * 32;            // u16
    constexpr int SMSZ = (MODE == 0) ? (128 * 136) : (ASZ + 2 * 128 * 32);
    __shared__ __align__(16) u16 smem[SMSZ];
    u16* AsB = smem;                            // [2][BM*32]
    u16* BsB = smem + ASZ;                      // [2][128*32]

    const int tid  = threadIdx.x;
    const int bm0  = blockIdx.x * BM;
    const int bn0  = blockIdx.y * 128;
    const int wave = tid >> 6, lane = tid & 63;
    const int l16  = lane & 15, quad = lane >> 4;
    const int wr   = (MODE == 1) ? 0 : (wave & 1) * 64;
    const int wc   = (MODE == 1) ? wave * 32 : (wave >> 1) * 64;

    const int srow = (lane >> 2);            // 0..15
    const int scol = (lane & 3) * 8;         // 0,8,16,24
    const int arow = (MODE == 1) ? (wave * 16) : (wave * 32);
    const float* Af = (const float*)Araw + (size_t)(bm0 + arow + srow) * K + scol;
    const u16*   Ab = (const u16*)Araw + (size_t)(bm0 + arow + srow) * K + scol;
    const u16* Bg = Bt + (size_t)(bn0 + wave * 32 + srow) * K + scol;
    const int wofsA = arow * 32;
    const int wofsB = (wave * 32) * 32;
    const int adst  = wofsA + lane * 8;      // u16 idx (matches glds16 layout)

    f32x4 acc[4][NI];
    #pragma unroll
    for (int i = 0; i < 4; ++i)
        #pragma unroll
        for (int j = 0; j < NI; ++j)
            acc[i][j] = (f32x4){0.f, 0.f, 0.f, 0.f};

    // ---- prologue: stage buf0 ----
    if (MODE == 0) {
        float4 a0 = *(const float4*)(Af);
        float4 a1 = *(const float4*)(Af + 4);
        float4 a2 = *(const float4*)(Af + 16 * K);
        float4 a3 = *(const float4*)(Af + 16 * K + 4);
        union { uint4 v; u16 s[8]; } o0, o1;
        o0.s[0]=f2bf(a0.x); o0.s[1]=f2bf(a0.y); o0.s[2]=f2bf(a0.z); o0.s[3]=f2bf(a0.w);
        o0.s[4]=f2bf(a1.x); o0.s[5]=f2bf(a1.y); o0.s[6]=f2bf(a1.z); o0.s[7]=f2bf(a1.w);
        o1.s[0]=f2bf(a2.x); o1.s[1]=f2bf(a2.y); o1.s[2]=f2bf(a2.z); o1.s[3]=f2bf(a2.w);
        o1.s[4]=f2bf(a3.x); o1.s[5]=f2bf(a3.y); o1.s[6]=f2bf(a3.z); o1.s[7]=f2bf(a3.w);
        *(uint4*)(&AsB[adst])           = o0.v;
        *(uint4*)(&AsB[adst + 16 * 32]) = o1.v;
    } else {
        glds16(Ab, &AsB[wofsA]);
    }
    glds16(Bg,                  &BsB[wofsB]);
    glds16(Bg + (size_t)16 * K, &BsB[wofsB + 16 * 32]);
    __syncthreads();

    const int NIT = K >> 5;
    for (int it = 0; it < NIT; ++it) {
        const int cur = it & 1;
        const bool pf = (it + 1 < NIT);
        float4 a0, a1, a2, a3;
        if (pf) {
            const int nx = cur ^ 1;
            const int k0 = (it + 1) << 5;
            glds16(Bg + k0,                  &BsB[nx * 4096 + wofsB]);
            glds16(Bg + k0 + (size_t)16 * K, &BsB[nx * 4096 + wofsB + 16 * 32]);
            if (MODE == 0) {                 // issue A loads early (latency hides
                a0 = *(const float4*)(Af + k0);              // under the MFMAs)
                a1 = *(const float4*)(Af + k0 + 4);
                a2 = *(const float4*)(Af + k0 + 16 * K);
                a3 = *(const float4*)(Af + k0 + 16 * K + 4);
            } else {
                glds16(Ab + k0, &AsB[nx * (BM * 32) + wofsA]);
            }
        }

        bf16x8 af[4], bfr[NI];
        #pragma unroll
        for (int mi = 0; mi < 4; ++mi)
            af[mi] = *(const bf16x8*)(&AsB[cur * (BM * 32) + (wr + mi * 16 + l16) * 32 + quad * 8]);
        #pragma unroll
        for (int ni = 0; ni < NI; ++ni)
            bfr[ni] = *(const bf16x8*)(&BsB[cur * 4096 + (wc + ni * 16 + l16) * 32 + quad * 8]);
        #pragma unroll
        for (int mi = 0; mi < 4; ++mi)
            #pragma unroll
            for (int ni = 0; ni < NI; ++ni)
                acc[mi][ni] = __builtin_amdgcn_mfma_f32_16x16x32_bf16(
                    af[mi], bfr[ni], acc[mi][ni], 0, 0, 0);

        if (pf && MODE == 0) {               // convert + LDS write after compute
            const int nx = cur ^ 1;
            union { uint4 v; u16 s[8]; } o0, o1;
            o0.s[0]=f2bf(a0.x); o0.s[1]=f2bf(a0.y); o0.s[2]=f2bf(a0.z); o0.s[3]=f2bf(a0.w);
            o0.s[4]=f2bf(a1.x); o0.s[5]=f2bf(a1.y); o0.s[6]=f2bf(a1.z); o0.s[7]=f2bf(a1.w);
            o1.s[0]=f2bf(a2.x); o1.s[1]=f2bf(a2.y); o1.s[2]=f2bf(a2.z); o1.s[3]=f2bf(a2.w);
            o1.s[4]=f2bf(a3.x); o1.s[5]=f2bf(a3.y); o1.s[6]=f2bf(a3.z); o1.s[7]=f2bf(a3.w);
            *(uint4*)(&AsB[nx * 4096 + adst])           = o0.v;
            *(uint4*)(&AsB[nx * 4096 + adst + 16 * 32]) = o1.v;
        }
        __syncthreads();
    }

    if (MODE == 0 && bn0 >= 1024) {
        // ---- V^T block: transpose 128x128 through LDS, coalesced stores ----
        u16* T = smem;                               // [128][136]
        #pragma unroll
        for (int mi = 0; mi < 4; ++mi) {
            #pragma unroll
            for (int ni = 0; ni < NI; ++ni) {
                int colL = wc + ni * 16 + l16;
                float bv = bias[bn0 + colL];
                int rowL = wr + mi * 16 + quad * 4;
                union { u16 q[4]; uint2 u; } pk;
                #pragma unroll
                for (int reg = 0; reg < 4; ++reg)
                    pk.q[reg] = f2bf(acc[mi][ni][reg] + bv);
                *(uint2*)(&T[(size_t)colL * 136 + rowL]) = pk.u;
            }
        }
        __syncthreads();
        u16* ws2 = (u16*)outv + (size_t)2 * PART;
        const int vn0 = bn0 - 1024;
        const int b = bm0 >> 11;
        const int s0v = bm0 & 2047;              // within-batch seq offset (R8 fix)
        const int colL = tid >> 1, half = tid & 1;
        const int wi = vn0 + colL, h = wi >> 6, e = wi & 63;
        u16* dst = ws2 + ((size_t)(b * NH + h) * HD + e) * SEQ + s0v + half * 64;
        #pragma unroll
        for (int j = 0; j < 8; ++j) {
            *(uint4*)(dst + j * 8) =
                *(const uint4*)(&T[(size_t)colL * 136 + half * 64 + j * 8]);
        }
        return;
    }

    #pragma unroll
    for (int mi = 0; mi < 4; ++mi) {
        #pragma unroll
        for (int ni = 0; ni < NI; ++ni) {
            int col = bn0 + wc + ni * 16 + l16;
            float bv = bias[col];
            int row0 = bm0 + wr + mi * 16 + quad * 4;
            float v[4];
            #pragma unroll
            for (int reg = 0; reg < 4; ++reg) v[reg] = acc[mi][ni][reg] + bv;

            if (MODE == 1) {
                #pragma unroll
                for (int reg = 0; reg < 4; ++reg)
                    ((float*)outv)[(size_t)(row0 + reg) * N + col] = v[reg];
            } else {
                u16* ws = (u16*)outv;
                int part = col >> 9, wi = col & 511;
                int h = wi >> 6, e = wi & 63;
                int b = row0 >> 11, s0 = row0 & 2047;
                float scl = (part == 0) ? QSCALE : 1.0f;
                #pragma unroll
                for (int reg = 0; reg < 4; ++reg)
                    ws[(size_t)part * PART +
                       ((size_t)(b * NH + h) * SEQ + s0 + reg) * HD + e] =
                        f2bf(v[reg] * scl);
            }
        }
    }
}

// ---------------------------------------------------------------------------
// Causal flash attention (R4 structure, best measured): swapped-QK 32x32
// MFMA, in-register P, grid (bh=32, y=32) one 64q-tile per block (qt=31-y,
// big-first LPT), 2 LDS buffers, launch_bounds(256,4) -> 4 blocks/CU.
// ---------------------------------------------------------------------------
__global__ __launch_bounds__(256, 4) void attn_k(
    const u16* __restrict__ Q, const u16* __restrict__ K,
    const u16* __restrict__ Vt, u16* __restrict__ O)
{
    __shared__ __align__(16) u16 KsB[2][64 * 64];   // [kv][d], chunk-swizzled
    __shared__ __align__(16) u16 VtB[2][64 * 64];   // [d][kv], chunk-swizzled
    __shared__ float Lred[4][32];

    const int bh = blockIdx.x;
    const int qt = 31 - blockIdx.y;            // big q-tiles dispatched first
    const int tid = threadIdx.x, wave = tid >> 6, lane = tid & 63;
    const int l31 = lane & 31, hi = lane >> 5, x7 = lane & 7;
    const int qh = wave >> 1, kh = wave & 1;
    const size_t baseK = (size_t)bh * SEQ * HD;
    const size_t baseV = (size_t)bh * HD * SEQ;
    const int b = bh >> 3, h = bh & 7;

    // glds lane source addressing (XOR chunk swizzle at the source)
    const int sub = lane >> 3;                 // 0..7
    const int lcx = (lane & 7) ^ sub;          // logical 16B chunk for this lane
    const u16* kg = K  + baseK + (size_t)((wave * 16 + sub) * 64)   + lcx * 8;
    const u16* vg = Vt + baseV + (size_t)((wave * 16 + sub) * 2048) + lcx * 8;
    u16* ksd = &KsB[0][wave * 1024];
    u16* vtd = &VtB[0][wave * 1024];

    // fragment LDS element offsets (swizzle: phys chunk = logical ^ (row&7))
    int koff[4], voff[2][2];
    #pragma unroll
    for (int k = 0; k < 4; ++k)
        koff[k] = (kh * 32 + l31) * 64 + ((((k << 1) + hi)) ^ x7) * 8;
    #pragma unroll
    for (int dt = 0; dt < 2; ++dt)
        #pragma unroll
        for (int k0 = 0; k0 < 2; ++k0)
            voff[dt][k0] = (dt * 32 + l31) * 64 + ((kh * 4 + k0 * 2 + hi) ^ x7) * 8;

    // ---- Q fragments direct from global (rows q = qt*64 + qh*32 + l31) ----
    const u16* qg = Q + baseK + (size_t)(qt * 64 + qh * 32 + l31) * 64 + hi * 8;
    bf16x8 qf[4];
    #pragma unroll
    for (int k = 0; k < 4; ++k)
        qf[k] = *(const bf16x8*)(qg + k * 16);

    // prefetch kt=0 into buffer 0
    glds16(kg,            ksd);
    glds16(kg + 8 * 64,   ksd + 512);
    glds16(vg,            vtd);
    glds16(vg + 8 * 2048, vtd + 512);
    __syncthreads();   // vmcnt(0) drain: buf0 landed

    float la0 = 0.f, la1 = 0.f;
    f32x16 o0, o1;
    #pragma unroll
    for (int i = 0; i < 16; ++i) { o0[i] = 0.f; o1[i] = 0.f; }

    for (int kt = 0; kt <= qt; ++kt) {
        const int cur = kt & 1;
        if (kt < qt) {
            const int nx = (cur ^ 1) * 4096;
            glds16(kg + (size_t)(kt + 1) * 4096,          ksd + nx);
            glds16(kg + (size_t)(kt + 1) * 4096 + 8 * 64, ksd + nx + 512);
            glds16(vg + (size_t)(kt + 1) * 64,            vtd + nx);
            glds16(vg + (size_t)(kt + 1) * 64 + 8 * 2048, vtd + nx + 512);
        }

        const bool diag = (kt == qt);
        if (!(diag && kh > qh)) {        // (qh=0,kh=1) diag tile fully masked
            bf16x8 kf[4], vf[2][2];
            #pragma unroll
            for (int k = 0; k < 4; ++k)
                kf[k] = *(const bf16x8*)(&KsB[cur][koff[k]]);
            #pragma unroll
            for (int dt = 0; dt < 2; ++dt)
                #pragma unroll
                for (int k0 = 0; k0 < 2; ++k0)
                    vf[dt][k0] = *(const bf16x8*)(&VtB[cur][voff[dt][k0]]);

            // S^T = K @ Q^T : col = q (lane&31), row = kv
            f32x16 st;
            #pragma unroll
            for (int i = 0; i < 16; ++i) st[i] = 0.f;
            __builtin_amdgcn_s_setprio(1);
            #pragma unroll
            for (int k = 0; k < 4; ++k)
                st = __builtin_amdgcn_mfma_f32_32x32x16_bf16(
                    kf[k], qf[k], st, 0, 0, 0);
            __builtin_amdgcn_s_setprio(0);

            // p[r] at kv_local = (r&3) + 8*(r>>2) + 4*hi, q = l31
            float p[16];
            #pragma unroll
            for (int r = 0; r < 16; ++r)
                p[r] = __builtin_amdgcn_exp2f(st[r]);
            if (diag && kh == qh) {      // triangular mask on the diagonal
                #pragma unroll
                for (int r = 0; r < 16; ++r) {
                    int kvl = (r & 3) + 8 * (r >> 2) + 4 * hi;
                    if (kvl > l31) p[r] = 0.f;
                }
            }
            #pragma unroll
            for (int r = 0; r < 8; ++r) { la0 += p[r]; la1 += p[r + 8]; }

            // pack to bf16 pairs; permlane32_swap builds PV A-fragments
            u32 c[8];
            #pragma unroll
            for (int m = 0; m < 8; ++m) {
                __hip_bfloat162 t =
                    __float22bfloat162_rn(float2{p[2 * m], p[2 * m + 1]});
                c[m] = *(u32*)&t;
            }
            pl32swap(c[0], c[2]); pl32swap(c[1], c[3]);
            pl32swap(c[4], c[6]); pl32swap(c[5], c[7]);
            union { u32 w[4]; bf16x8 v; } pa0, pa1;
            pa0.w[0] = c[0]; pa0.w[1] = c[1]; pa0.w[2] = c[2]; pa0.w[3] = c[3];
            pa1.w[0] = c[4]; pa1.w[1] = c[5]; pa1.w[2] = c[6]; pa1.w[3] = c[7];

            // O[q][d] += P @ V   (A = P, B = V from Vt tile)
            __builtin_amdgcn_s_setprio(1);
            o0 = __builtin_amdgcn_mfma_f32_32x32x16_bf16(pa0.v, vf[0][0], o0, 0, 0, 0);
            o0 = __builtin_amdgcn_mfma_f32_32x32x16_bf16(pa1.v, vf[0][1], o0, 0, 0, 0);
            o1 = __builtin_amdgcn_mfma_f32_32x32x16_bf16(pa0.v, vf[1][0], o1, 0, 0, 0);
            o1 = __builtin_amdgcn_mfma_f32_32x32x16_bf16(pa1.v, vf[1][1], o1, 0, 0, 0);
            __builtin_amdgcn_s_setprio(0);
        }
        __syncthreads();   // all waves done with buf[cur]; prefetch drained
    }

    // ---- merge kv-halves (pure sums): l via Lred, o via K/V LDS reuse ----
    float l2 = (la0 + la1);
    l2 += __shfl_xor(l2, 32);            // combine hi halves (same q)
    if (lane < 32) Lred[wave][lane] = l2;
    float* Ob = (qh == 0) ? (float*)&KsB[0][0] : (float*)&VtB[0][0];
    if (kh == 1) {
        #pragma unroll
        for (int r = 0; r < 16; ++r) {
            Ob[r * 64 + lane]        = o0[r];
            Ob[(16 + r) * 64 + lane] = o1[r];
        }
    }
    __syncthreads();
    if (kh == 0) {
        #pragma unroll
        for (int r = 0; r < 16; ++r) {
            int ql = (r & 3) + 8 * (r >> 2) + 4 * hi;       // q row 0..31
            float lt = Lred[2 * qh][ql] + Lred[2 * qh + 1][ql];
            int srow = qt * 64 + qh * 32 + ql;
            size_t idx = (((size_t)(b * SEQ + srow)) * NH + h) * HD + l31;
            float v0 = (o0[r] + Ob[r * 64 + lane]) / lt;
            float v1 = (o1[r] + Ob[(16 + r) * 64 + lane]) / lt;
            O[idx]      = f2bf(v0);
            O[idx + 32] = f2bf(v1);
        }
    }
}

extern "C" void kernel_launch(void* const* d_in, const int* in_sizes, int n_in,
                              void* d_out, int out_size, void* d_ws, size_t ws_size,
                              hipStream_t stream) {
    const float* x     = (const float*)d_in[0];
    const float* w_qkv = (const float*)d_in[1];
    const float* b_qkv = (const float*)d_in[2];
    const float* w_out = (const float*)d_in[3];
    const float* b_out = (const float*)d_in[4];

    u16* qkv    = (u16*)d_ws;                       // Q | K | V^T, each PART
    u16* attn   = qkv + (size_t)3 * PART;           // PART bf16 (B,S,H,HD)
    u16* wt_qkv = attn + (size_t)PART;              // 1536*512 bf16
    u16* wt_out = wt_qkv + (size_t)(3 * DM) * DM;   // 512*512 bf16

    const int M = BATCH * SEQ;                      // 8192

    prep_k<<<dim3(192, 1, 2), 256, 0, stream>>>(w_qkv, wt_qkv, w_out, wt_out);

    dim3 g1(M / 128, (3 * DM) / 128);               // 64 x 12
    gemm_k<0><<<g1, 256, 0, stream>>>(x, wt_qkv, b_qkv, qkv, M, 3 * DM, DM);

    dim3 g2(BATCH * NH, 32);                        // bh x qt (big-first LPT)
    attn_k<<<g2, 256, 0, stream>>>(qkv, qkv + PART, qkv + 2 * (size_t)PART, attn);

    dim3 g3(M / 64, DM / 128);                      // 128 x 4 = 512 blocks
    gemm_k<1><<<g3, 256, 0, stream>>>(attn, wt_out, b_out, (float*)d_out, M, DM, DM);
}

// Round 10
// 149.998 us; speedup vs baseline: 1.1668x; 1.0010x over previous
//
#include <hip/hip_runtime.h>
#include <hip/hip_bf16.h>

#define BATCH 4
#define SEQ   2048
#define DM    512
#define NH    8
#define HD    64
#define PART  (BATCH*NH*SEQ*HD)   /* 4,194,304 = M*DM */
#define QSCALE 0.18033688f        /* (1/sqrt(64)) * log2(e) : folded into Q */

typedef unsigned short u16;
typedef unsigned int   u32;
typedef __bf16 bf16x8 __attribute__((ext_vector_type(8)));
typedef float  f32x4  __attribute__((ext_vector_type(4)));
typedef float  f32x16 __attribute__((ext_vector_type(16)));
typedef unsigned int u32x2 __attribute__((ext_vector_type(2)));

__device__ __forceinline__ u16 f2bf(float f) {
    union { float f; u32 u; } v; v.f = f;
    u32 r = v.u + 0x7fffu + ((v.u >> 16) & 1u);   // RNE
    return (u16)(r >> 16);
}

// async global->LDS, 16B per lane; LDS dest = uniform base + lane*16
__device__ __forceinline__ void glds16(const u16* g, u16* lds) {
    __builtin_amdgcn_global_load_lds(
        (const __attribute__((address_space(1))) void*)g,
        (__attribute__((address_space(3))) void*)lds, 16, 0, 0);
}

// v_permlane32_swap_b32: a.hi-lanes <-> b.lo-lanes
__device__ __forceinline__ void pl32swap(u32 &a, u32 &b) {
    u32x2 r = __builtin_amdgcn_permlane32_swap(a, b, false, false);
    a = r[0]; b = r[1];
}

// ---------------------------------------------------------------------------
// prep: z=0 -> f32->bf16 convert of x (512 blocks, grid-stride)
//       z=1 -> transpose w_qkv (192 blocks)   z=2 -> transpose w_out (64)
// (R4-verbatim: the R8/R9 A-fusion regressed; glds16 A-staging needs bf16 xb)
// ---------------------------------------------------------------------------
__global__ __launch_bounds__(256) void prep_k(
    const float* __restrict__ x, u16* __restrict__ xb,
    const float* __restrict__ w_qkv, u16* __restrict__ t_qkv,
    const float* __restrict__ w_out, u16* __restrict__ t_out)
{
    __shared__ u16 Ts[64][72];
    const int z = blockIdx.z, bx = blockIdx.x, t = threadIdx.x;

    if (z == 0) {
        const int n8 = PART / 8;
        for (int i = bx * 256 + t; i < n8; i += 512 * 256) {
            float4 a = *(const float4*)(x + (size_t)i * 8);
            float4 b = *(const float4*)(x + (size_t)i * 8 + 4);
            union { uint4 v; u16 s[8]; } o;
            o.s[0] = f2bf(a.x); o.s[1] = f2bf(a.y);
            o.s[2] = f2bf(a.z); o.s[3] = f2bf(a.w);
            o.s[4] = f2bf(b.x); o.s[5] = f2bf(b.y);
            o.s[6] = f2bf(b.z); o.s[7] = f2bf(b.w);
            *(uint4*)(xb + (size_t)i * 8) = o.v;
        }
        return;
    }
    const int N = (z == 1) ? 3 * DM : DM;
    const int ntiles = N / 64;
    if (bx >= ntiles * 8) return;
    const float* W = (z == 1) ? w_qkv : w_out;
    u16* Wt = (z == 1) ? t_qkv : t_out;
    const int n0 = (bx % ntiles) * 64, k0 = (bx / ntiles) * 64;

    #pragma unroll
    for (int l = 0; l < 4; ++l) {
        int idx = l * 1024 + t * 4;
        int r = idx >> 6, c = idx & 63;
        float4 v = *(const float4*)(W + (size_t)(k0 + r) * N + n0 + c);
        Ts[c + 0][r] = f2bf(v.x);
        Ts[c + 1][r] = f2bf(v.y);
        Ts[c + 2][r] = f2bf(v.z);
        Ts[c + 3][r] = f2bf(v.w);
    }
    __syncthreads();
    #pragma unroll
    for (int l = 0; l < 2; ++l) {
        int idx = l * 256 + t;
        int row = idx >> 3, ch = idx & 7;
        *(uint4*)(Wt + (size_t)(n0 + row) * DM + k0 + ch * 8) =
            *(const uint4*)(&Ts[row][ch * 8]);
    }
}

// ---------------------------------------------------------------------------
// GEMM: C(M,N) = A(M,K)bf16 @ Bt(N,K)^T bf16 + bias(N)f32.
// K-loop = R4-verbatim (glds16 double-buffer, one barrier per K-step).
// MODE 0 epilogue REWORKED: all parts store through an LDS-staged tile with
// fully-coalesced uint4 global stores.
//   Q/K parts: tile rows are adjacent in s -> per-head output region is a
//   CONTIGUOUS 16 KB run. Row-major T[128][136], then 8 uint4 stores/thread
//   (was 64 scalar u16 scatter-stores/thread).
//   V^T part: col-major T (s contiguous per (h,e) run), R9 path + s0v fix.
// MODE 1: BM=64; row-major f32 store. (unchanged)
// ---------------------------------------------------------------------------
template<int MODE>
__global__ __launch_bounds__(256) void gemm_k(
    const u16* __restrict__ A, const u16* __restrict__ Bt,
    const float* __restrict__ bias, void* __restrict__ outv,
    int M, int N, int K)
{
    constexpr int BM = (MODE == 1) ? 64 : 128;
    constexpr int NI = (MODE == 1) ? 2 : 4;
    constexpr int ABUF = BM * 32;               // u16 per A buffer
    constexpr int SMSZ = (MODE == 0) ? (128 * 136) : (2 * ABUF + 2 * 128 * 32);
    __shared__ __align__(16) u16 smem[SMSZ];
    u16* AsB = smem;                            // [2][ABUF]
    u16* BsB = smem + 2 * ABUF;                 // [2][4096]

    const int tid  = threadIdx.x;
    const int bm0  = blockIdx.x * BM;
    const int bn0  = blockIdx.y * 128;
    const int wave = tid >> 6, lane = tid & 63;
    const int l16  = lane & 15, quad = lane >> 4;
    const int wr   = (MODE == 1) ? 0 : (wave & 1) * 64;
    const int wc   = (MODE == 1) ? wave * 32 : (wave >> 1) * 64;

    const int srow = (lane >> 2);            // 0..15
    const int scol = (lane & 3) * 8;         // 0,8,16,24
    const int arow = (MODE == 1) ? (wave * 16) : (wave * 32);
    const u16* Ag = A + (size_t)(bm0 + arow + srow) * K + scol;
    const u16* Bg = Bt + (size_t)(bn0 + wave * 32 + srow) * K + scol;
    const int wofsA = arow * 32;
    const int wofsB = (wave * 32) * 32;

    f32x4 acc[4][NI];
    #pragma unroll
    for (int i = 0; i < 4; ++i)
        #pragma unroll
        for (int j = 0; j < NI; ++j)
            acc[i][j] = (f32x4){0.f, 0.f, 0.f, 0.f};

    glds16(Ag, &AsB[wofsA]);
    if (MODE == 0) glds16(Ag + (size_t)16 * K, &AsB[wofsA + 16 * 32]);
    glds16(Bg,                  &BsB[wofsB]);
    glds16(Bg + (size_t)16 * K, &BsB[wofsB + 16 * 32]);
    __syncthreads();

    const int NIT = K >> 5;
    for (int it = 0; it < NIT; ++it) {
        const int cur = it & 1;
        if (it + 1 < NIT) {
            const int nx = cur ^ 1;
            const int k0 = (it + 1) << 5;
            glds16(Ag + k0, &AsB[nx * ABUF + wofsA]);
            if (MODE == 0) glds16(Ag + k0 + (size_t)16 * K, &AsB[nx * ABUF + wofsA + 16 * 32]);
            glds16(Bg + k0,                  &BsB[nx * 4096 + wofsB]);
            glds16(Bg + k0 + (size_t)16 * K, &BsB[nx * 4096 + wofsB + 16 * 32]);
        }

        bf16x8 af[4], bfr[NI];
        #pragma unroll
        for (int mi = 0; mi < 4; ++mi)
            af[mi] = *(const bf16x8*)(&AsB[cur * ABUF + (wr + mi * 16 + l16) * 32 + quad * 8]);
        #pragma unroll
        for (int ni = 0; ni < NI; ++ni)
            bfr[ni] = *(const bf16x8*)(&BsB[cur * 4096 + (wc + ni * 16 + l16) * 32 + quad * 8]);
        #pragma unroll
        for (int mi = 0; mi < 4; ++mi)
            #pragma unroll
            for (int ni = 0; ni < NI; ++ni)
                acc[mi][ni] = __builtin_amdgcn_mfma_f32_16x16x32_bf16(
                    af[mi], bfr[ni], acc[mi][ni], 0, 0, 0);
        __syncthreads();
    }

    if (MODE == 0) {
        u16* ws = (u16*)outv;
        u16* T = smem;                           // [128][136] u16
        const int part = bn0 >> 9;               // 0=Q 1=K 2=V
        const int bb = bm0 >> 11, s0 = bm0 & 2047;

        if (part < 2) {
            // ---- Q/K: row-major T; per-head 16 KB contiguous stores ----
            const float scl = (part == 0) ? QSCALE : 1.0f;
            #pragma unroll
            for (int mi = 0; mi < 4; ++mi) {
                #pragma unroll
                for (int ni = 0; ni < NI; ++ni) {
                    int colL = wc + ni * 16 + l16;
                    float bv = bias[bn0 + colL];
                    int rowL = wr + mi * 16 + quad * 4;
                    #pragma unroll
                    for (int reg = 0; reg < 4; ++reg)
                        T[(rowL + reg) * 136 + colL] =
                            f2bf((acc[mi][ni][reg] + bv) * scl);
                }
            }
            __syncthreads();
            const int h0 = (bn0 & 511) >> 6;     // 0,2,4,6
            #pragma unroll
            for (int l = 0; l < 8; ++l) {
                int flat = l * 256 + tid;        // 0..2047
                int hl   = flat >> 10;           // 0..1
                int rem  = flat & 1023;
                int row  = rem >> 3, ch = rem & 7;
                u16* dst = ws + (size_t)part * PART +
                           ((size_t)(bb * NH + h0 + hl) * SEQ + s0 + row) * HD + ch * 8;
                *(uint4*)dst = *(const uint4*)(&T[row * 136 + hl * 64 + ch * 8]);
            }
        } else {
            // ---- V^T: col-major T; 256B-contiguous s-runs (R9 + s0v fix) ----
            #pragma unroll
            for (int mi = 0; mi < 4; ++mi) {
                #pragma unroll
                for (int ni = 0; ni < NI; ++ni) {
                    int colL = wc + ni * 16 + l16;
                    float bv = bias[bn0 + colL];
                    int rowL = wr + mi * 16 + quad * 4;
                    union { u16 q[4]; uint2 u; } pk;
                    #pragma unroll
                    for (int reg = 0; reg < 4; ++reg)
                        pk.q[reg] = f2bf(acc[mi][ni][reg] + bv);
                    *(uint2*)(&T[(size_t)colL * 136 + rowL]) = pk.u;
                }
            }
            __syncthreads();
            u16* ws2 = ws + (size_t)2 * PART;
            const int vn0 = bn0 - 1024;
            const int colL = tid >> 1, half = tid & 1;
            const int wi = vn0 + colL, h = wi >> 6, e = wi & 63;
            u16* dst = ws2 + ((size_t)(bb * NH + h) * HD + e) * SEQ + s0 + half * 64;
            #pragma unroll
            for (int j = 0; j < 8; ++j) {
                *(uint4*)(dst + j * 8) =
                    *(const uint4*)(&T[(size_t)colL * 136 + half * 64 + j * 8]);
            }
        }
        return;
    }

    #pragma unroll
    for (int mi = 0; mi < 4; ++mi) {
        #pragma unroll
        for (int ni = 0; ni < NI; ++ni) {
            int col = bn0 + wc + ni * 16 + l16;
            float bv = bias[col];
            int row0 = bm0 + wr + mi * 16 + quad * 4;
            #pragma unroll
            for (int reg = 0; reg < 4; ++reg)
                ((float*)outv)[(size_t)(row0 + reg) * N + col] =
                    acc[mi][ni][reg] + bv;
        }
    }
}

// ---------------------------------------------------------------------------
// Causal flash attention (R4 structure, best measured): swapped-QK 32x32
// MFMA, in-register P, grid (bh=32, y=32) one 64q-tile per block (qt=31-y,
// big-first LPT), 2 LDS buffers, launch_bounds(256,4) -> 4 blocks/CU.
// ---------------------------------------------------------------------------
__global__ __launch_bounds__(256, 4) void attn_k(
    const u16* __restrict__ Q, const u16* __restrict__ K,
    const u16* __restrict__ Vt, u16* __restrict__ O)
{
    __shared__ __align__(16) u16 KsB[2][64 * 64];   // [kv][d], chunk-swizzled
    __shared__ __align__(16) u16 VtB[2][64 * 64];   // [d][kv], chunk-swizzled
    __shared__ float Lred[4][32];

    const int bh = blockIdx.x;
    const int qt = 31 - blockIdx.y;            // big q-tiles dispatched first
    const int tid = threadIdx.x, wave = tid >> 6, lane = tid & 63;
    const int l31 = lane & 31, hi = lane >> 5, x7 = lane & 7;
    const int qh = wave >> 1, kh = wave & 1;
    const size_t baseK = (size_t)bh * SEQ * HD;
    const size_t baseV = (size_t)bh * HD * SEQ;
    const int b = bh >> 3, h = bh & 7;

    // glds lane source addressing (XOR chunk swizzle at the source)
    const int sub = lane >> 3;                 // 0..7
    const int lcx = (lane & 7) ^ sub;          // logical 16B chunk for this lane
    const u16* kg = K  + baseK + (size_t)((wave * 16 + sub) * 64)   + lcx * 8;
    const u16* vg = Vt + baseV + (size_t)((wave * 16 + sub) * 2048) + lcx * 8;
    u16* ksd = &KsB[0][wave * 1024];
    u16* vtd = &VtB[0][wave * 1024];

    // fragment LDS element offsets (swizzle: phys chunk = logical ^ (row&7))
    int koff[4], voff[2][2];
    #pragma unroll
    for (int k = 0; k < 4; ++k)
        koff[k] = (kh * 32 + l31) * 64 + ((((k << 1) + hi)) ^ x7) * 8;
    #pragma unroll
    for (int dt = 0; dt < 2; ++dt)
        #pragma unroll
        for (int k0 = 0; k0 < 2; ++k0)
            voff[dt][k0] = (dt * 32 + l31) * 64 + ((kh * 4 + k0 * 2 + hi) ^ x7) * 8;

    // ---- Q fragments direct from global (rows q = qt*64 + qh*32 + l31) ----
    const u16* qg = Q + baseK + (size_t)(qt * 64 + qh * 32 + l31) * 64 + hi * 8;
    bf16x8 qf[4];
    #pragma unroll
    for (int k = 0; k < 4; ++k)
        qf[k] = *(const bf16x8*)(qg + k * 16);

    // prefetch kt=0 into buffer 0
    glds16(kg,            ksd);
    glds16(kg + 8 * 64,   ksd + 512);
    glds16(vg,            vtd);
    glds16(vg + 8 * 2048, vtd + 512);
    __syncthreads();   // vmcnt(0) drain: buf0 landed

    float la0 = 0.f, la1 = 0.f;
    f32x16 o0, o1;
    #pragma unroll
    for (int i = 0; i < 16; ++i) { o0[i] = 0.f; o1[i] = 0.f; }

    for (int kt = 0; kt <= qt; ++kt) {
        const int cur = kt & 1;
        if (kt < qt) {
            const int nx = (cur ^ 1) * 4096;
            glds16(kg + (size_t)(kt + 1) * 4096,          ksd + nx);
            glds16(kg + (size_t)(kt + 1) * 4096 + 8 * 64, ksd + nx + 512);
            glds16(vg + (size_t)(kt + 1) * 64,            vtd + nx);
            glds16(vg + (size_t)(kt + 1) * 64 + 8 * 2048, vtd + nx + 512);
        }

        const bool diag = (kt == qt);
        if (!(diag && kh > qh)) {        // (qh=0,kh=1) diag tile fully masked
            bf16x8 kf[4], vf[2][2];
            #pragma unroll
            for (int k = 0; k < 4; ++k)
                kf[k] = *(const bf16x8*)(&KsB[cur][koff[k]]);
            #pragma unroll
            for (int dt = 0; dt < 2; ++dt)
                #pragma unroll
                for (int k0 = 0; k0 < 2; ++k0)
                    vf[dt][k0] = *(const bf16x8*)(&VtB[cur][voff[dt][k0]]);

            // S^T = K @ Q^T : col = q (lane&31), row = kv
            f32x16 st;
            #pragma unroll
            for (int i = 0; i < 16; ++i) st[i] = 0.f;
            __builtin_amdgcn_s_setprio(1);
            #pragma unroll
            for (int k = 0; k < 4; ++k)
                st = __builtin_amdgcn_mfma_f32_32x32x16_bf16(
                    kf[k], qf[k], st, 0, 0, 0);
            __builtin_amdgcn_s_setprio(0);

            // p[r] at kv_local = (r&3) + 8*(r>>2) + 4*hi, q = l31
            float p[16];
            #pragma unroll
            for (int r = 0; r < 16; ++r)
                p[r] = __builtin_amdgcn_exp2f(st[r]);
            if (diag && kh == qh) {      // triangular mask on the diagonal
                #pragma unroll
                for (int r = 0; r < 16; ++r) {
                    int kvl = (r & 3) + 8 * (r >> 2) + 4 * hi;
                    if (kvl > l31) p[r] = 0.f;
                }
            }
            #pragma unroll
            for (int r = 0; r < 8; ++r) { la0 += p[r]; la1 += p[r + 8]; }

            // pack to bf16 pairs; permlane32_swap builds PV A-fragments
            u32 c[8];
            #pragma unroll
            for (int m = 0; m < 8; ++m) {
                __hip_bfloat162 t =
                    __float22bfloat162_rn(float2{p[2 * m], p[2 * m + 1]});
                c[m] = *(u32*)&t;
            }
            pl32swap(c[0], c[2]); pl32swap(c[1], c[3]);
            pl32swap(c[4], c[6]); pl32swap(c[5], c[7]);
            union { u32 w[4]; bf16x8 v; } pa0, pa1;
            pa0.w[0] = c[0]; pa0.w[1] = c[1]; pa0.w[2] = c[2]; pa0.w[3] = c[3];
            pa1.w[0] = c[4]; pa1.w[1] = c[5]; pa1.w[2] = c[6]; pa1.w[3] = c[7];

            // O[q][d] += P @ V   (A = P, B = V from Vt tile)
            __builtin_amdgcn_s_setprio(1);
            o0 = __builtin_amdgcn_mfma_f32_32x32x16_bf16(pa0.v, vf[0][0], o0, 0, 0, 0);
            o0 = __builtin_amdgcn_mfma_f32_32x32x16_bf16(pa1.v, vf[0][1], o0, 0, 0, 0);
            o1 = __builtin_amdgcn_mfma_f32_32x32x16_bf16(pa0.v, vf[1][0], o1, 0, 0, 0);
            o1 = __builtin_amdgcn_mfma_f32_32x32x16_bf16(pa1.v, vf[1][1], o1, 0, 0, 0);
            __builtin_amdgcn_s_setprio(0);
        }
        __syncthreads();   // all waves done with buf[cur]; prefetch drained
    }

    // ---- merge kv-halves (pure sums): l via Lred, o via K/V LDS reuse ----
    float l2 = (la0 + la1);
    l2 += __shfl_xor(l2, 32);            // combine hi halves (same q)
    if (lane < 32) Lred[wave][lane] = l2;
    float* Ob = (qh == 0) ? (float*)&KsB[0][0] : (float*)&VtB[0][0];
    if (kh == 1) {
        #pragma unroll
        for (int r = 0; r < 16; ++r) {
            Ob[r * 64 + lane]        = o0[r];
            Ob[(16 + r) * 64 + lane] = o1[r];
        }
    }
    __syncthreads();
    if (kh == 0) {
        #pragma unroll
        for (int r = 0; r < 16; ++r) {
            int ql = (r & 3) + 8 * (r >> 2) + 4 * hi;       // q row 0..31
            float lt = Lred[2 * qh][ql] + Lred[2 * qh + 1][ql];
            int srow = qt * 64 + qh * 32 + ql;
            size_t idx = (((size_t)(b * SEQ + srow)) * NH + h) * HD + l31;
            float v0 = (o0[r] + Ob[r * 64 + lane]) / lt;
            float v1 = (o1[r] + Ob[(16 + r) * 64 + lane]) / lt;
            O[idx]      = f2bf(v0);
            O[idx + 32] = f2bf(v1);
        }
    }
}

extern "C" void kernel_launch(void* const* d_in, const int* in_sizes, int n_in,
                              void* d_out, int out_size, void* d_ws, size_t ws_size,
                              hipStream_t stream) {
    const float* x     = (const float*)d_in[0];
    const float* w_qkv = (const float*)d_in[1];
    const float* b_qkv = (const float*)d_in[2];
    const float* w_out = (const float*)d_in[3];
    const float* b_out = (const float*)d_in[4];

    u16* qkv    = (u16*)d_ws;                       // Q | K | V^T, each PART
    u16* attn   = qkv + (size_t)3 * PART;           // PART bf16 (B,S,H,HD)
    u16* xb     = attn + (size_t)PART;              // PART bf16 (x converted)
    u16* wt_qkv = xb + (size_t)PART;                // 1536*512 bf16
    u16* wt_out = wt_qkv + (size_t)(3 * DM) * DM;   // 512*512 bf16

    const int M = BATCH * SEQ;                      // 8192

    prep_k<<<dim3(512, 1, 3), 256, 0, stream>>>(x, xb, w_qkv, wt_qkv,
                                                w_out, wt_out);

    dim3 g1(M / 128, (3 * DM) / 128);               // 64 x 12
    gemm_k<0><<<g1, 256, 0, stream>>>(xb, wt_qkv, b_qkv, qkv, M, 3 * DM, DM);

    dim3 g2(BATCH * NH, 32);                        // bh x qt (big-first LPT)
    attn_k<<<g2, 256, 0, stream>>>(qkv, qkv + PART, qkv + 2 * (size_t)PART, attn);

    dim3 g3(M / 64, DM / 128);                      // 128 x 4 = 512 blocks
    gemm_k<1><<<g3, 256, 0, stream>>>(attn, wt_out, b_out, (float*)d_out, M, DM, DM);
}